// Round 5
// baseline (432.206 us; speedup 1.0000x reference)
//
#include <hip/hip_runtime.h>
#include <math.h>

typedef __attribute__((ext_vector_type(8))) short short8;
typedef __attribute__((ext_vector_type(4))) float floatx4;
typedef __attribute__((ext_vector_type(4))) unsigned short ushort4v;

__device__ __forceinline__ void load_lds16(const void* g, void* l) {
    __builtin_amdgcn_global_load_lds((const __attribute__((address_space(1))) void*)g,
                                     (__attribute__((address_space(3))) void*)l,
                                     16, 0, 0);
}

__device__ __forceinline__ unsigned short f2bf(float x) {
    union { float f; unsigned int u; } v; v.f = x;
    unsigned int r = v.u + 0x7fffu + ((v.u >> 16) & 1u);
    return (unsigned short)(r >> 16);
}

__device__ __forceinline__ float sigm(float x) { return 1.0f / (1.0f + __expf(-x)); }

// ---- fused prep: weight bf16 conversions + Toeplitz XW build ----
// blocks: [0,1024) w0 | [1024,13312) w | [13312,15360) wf-pad | [15360,17408) XW
__global__ void prep(const float* __restrict__ w0, const float* __restrict__ w,
                     const float* __restrict__ wf, const float* __restrict__ xi,
                     unsigned short* __restrict__ w0d, unsigned short* __restrict__ wd,
                     unsigned short* __restrict__ wfd, unsigned int* __restrict__ xw) {
    const int bid = blockIdx.x;
    if (bid < 1024) {
        int i = bid * 256 + threadIdx.x;
        float4 v = ((const float4*)w0)[i];
        ((ushort4v*)w0d)[i] = (ushort4v){ f2bf(v.x), f2bf(v.y), f2bf(v.z), f2bf(v.w) };
    } else if (bid < 13312) {
        int i = (bid - 1024) * 256 + threadIdx.x;
        float4 v = ((const float4*)w)[i];
        ((ushort4v*)wd)[i] = (ushort4v){ f2bf(v.x), f2bf(v.y), f2bf(v.z), f2bf(v.w) };
    } else if (bid < 15360) {
        int idx = (bid - 13312) * 256 + threadIdx.x;
        int e = idx * 4;
        int m = e >> 15, r = (e >> 8) & 127, c = e & 255;
        ushort4v o = {0, 0, 0, 0};
        if (r < 65) {
            float4 v = *(const float4*)&wf[((size_t)m * 65 + r) * 256 + c];
            o = (ushort4v){ f2bf(v.x), f2bf(v.y), f2bf(v.z), f2bf(v.w) };
        }
        ((ushort4v*)wfd)[idx] = o;
    } else {
        const int k = bid - 15360;
        const int m = k >> 5;
        const int n0 = (k & 31) * 128;
        const float* xim = xi + (size_t)m * 4160;
        for (int t = 0; t < 17; ++t) {
            const int d = threadIdx.x * 17 + t;
            const int row = d / 34;
            const int pos = d - row * 34;
            const int n = n0 + row;
            const int j0 = pos * 2;
            const float v0 = (j0 < 65) ? xim[n + j0] : 0.0f;
            const float v1 = (j0 + 1 < 65) ? xim[n + j0 + 1] : 0.0f;
            xw[(size_t)n * 2176 + (size_t)m * 34 + pos] =
                (unsigned int)f2bf(v0) | ((unsigned int)f2bf(v1) << 16);
        }
    }
}

// ---- one MLP layer: MFMA phase only (weights direct from global/L2, X from LDS) ----
// X layout: X[b][k] at b*K + ((k/8) ^ (b&7))*8 + (k&7)   (shorts)
template<int K, int I>
__device__ __forceinline__ void mlp_mfma(
    const unsigned short* __restrict__ Wm, const unsigned short* src,
    int wave, int lane, floatx4 (*acc)[4])
{
    const int quad = lane >> 4, l16 = lane & 15;
    const int rbw = wave * (I * 16);
    const floatx4 zero = {0.f, 0.f, 0.f, 0.f};
    #pragma unroll
    for (int i = 0; i < I; ++i)
        #pragma unroll
        for (int j = 0; j < 4; ++j) acc[i][j] = zero;

    short8 af[I];
    #pragma unroll
    for (int i = 0; i < I; ++i)
        af[i] = *(const short8*)&Wm[(size_t)(rbw + i * 16 + l16) * K + quad * 8];

    #pragma unroll
    for (int kk = 0; kk < K / 32; ++kk) {
        short8 afn[I];
        if (kk + 1 < K / 32) {
            #pragma unroll
            for (int i = 0; i < I; ++i)
                afn[i] = *(const short8*)&Wm[(size_t)(rbw + i * 16 + l16) * K + (kk + 1) * 32 + quad * 8];
        }
        short8 bf[4];
        #pragma unroll
        for (int j = 0; j < 4; ++j) {
            const int cb = j * 16 + l16;
            bf[j] = *(const short8*)&src[cb * K + (((kk * 4 + quad) ^ (cb & 7)) * 8)];
        }
        #pragma unroll
        for (int i = 0; i < I; ++i)
            #pragma unroll
            for (int j = 0; j < 4; ++j)
                acc[i][j] = __builtin_amdgcn_mfma_f32_16x16x32_bf16(af[i], bf[j], acc[i][j], 0, 0, 0);
        #pragma unroll
        for (int i = 0; i < I; ++i) af[i] = afn[i];
    }
}

// epilogue: bias+sigmoid+bf16, write back into the SAME X buffer (K_out=256 layout)
__device__ __forceinline__ void mlp_write(
    const float* __restrict__ bm, unsigned short* dst,
    int wave, int lane, floatx4 (*acc)[4])
{
    const int quad = lane >> 4, l16 = lane & 15;
    const int rbw = wave * 64;
    #pragma unroll
    for (int i = 0; i < 4; ++i) {
        const int rb = rbw + i * 16 + quad * 4;
        float bv0 = bm[rb], bv1 = bm[rb + 1], bv2 = bm[rb + 2], bv3 = bm[rb + 3];
        #pragma unroll
        for (int j = 0; j < 4; ++j) {
            const int cb = j * 16 + l16;
            ushort4v o;
            o[0] = f2bf(sigm(acc[i][j][0] + bv0));
            o[1] = f2bf(sigm(acc[i][j][1] + bv1));
            o[2] = f2bf(sigm(acc[i][j][2] + bv2));
            o[3] = f2bf(sigm(acc[i][j][3] + bv3));
            // note: ~12 extra cyc/instr 4-way bank conflict here (quad-pair overlay) — second-order
            *(ushort4v*)&dst[cb * 256 + (((rb >> 3) ^ (cb & 7)) * 8) + (rb & 7)] = o;
        }
    }
}

// ---- fused MLP: all 5 layers, single 32 KB in-place activation buffer ----
// grid 1024 = 64 m x 16 batch-tiles (XCD-swizzled), 256 threads, 4 blocks/CU.
__global__ __launch_bounds__(256, 4)
void fused_mlp(const float* __restrict__ u,
               const unsigned short* __restrict__ w0_bf, const float* __restrict__ b0_,
               const unsigned short* __restrict__ w_bf,  const float* __restrict__ b_,
               const unsigned short* __restrict__ wf_bf, const float* __restrict__ bf_,
               unsigned short* __restrict__ Gflat) {
    __shared__ unsigned short X[64 * 256];   // 32 KB, in-place across layers

    const int bid = blockIdx.x;
    const int xcd = bid & 7, slot = bid >> 3;
    const int m  = (xcd << 3) + (slot >> 4);
    const int b0 = (slot & 15) << 6;
    const int tid = threadIdx.x, wave = tid >> 6, lane = tid & 63;

    // stage u (fp32) -> X (bf16, K=64 layout)
    {
        const int b = tid >> 2, dc = tid & 3;
        const float* up = u + (size_t)(b0 + b) * 64 + dc * 16;
        float4 v0 = *(const float4*)(up);
        float4 v1 = *(const float4*)(up + 4);
        float4 v2 = *(const float4*)(up + 8);
        float4 v3 = *(const float4*)(up + 12);
        short8 c0 = { (short)f2bf(v0.x), (short)f2bf(v0.y), (short)f2bf(v0.z), (short)f2bf(v0.w),
                      (short)f2bf(v1.x), (short)f2bf(v1.y), (short)f2bf(v1.z), (short)f2bf(v1.w) };
        short8 c1 = { (short)f2bf(v2.x), (short)f2bf(v2.y), (short)f2bf(v2.z), (short)f2bf(v2.w),
                      (short)f2bf(v3.x), (short)f2bf(v3.y), (short)f2bf(v3.z), (short)f2bf(v3.w) };
        *(short8*)&X[b * 64 + (((dc * 2)     ^ (b & 7)) * 8)] = c0;
        *(short8*)&X[b * 64 + (((dc * 2 + 1) ^ (b & 7)) * 8)] = c1;
    }
    __syncthreads();

    floatx4 acc[4][4];

    // layer 0 (K=64)
    mlp_mfma<64, 4>(w0_bf + (size_t)m * 16384, X, wave, lane, acc);
    __syncthreads();
    mlp_write(b0_ + (size_t)m * 256, X, wave, lane, acc);
    __syncthreads();

    // hidden layers 1..3 (K=256)
    #pragma unroll 1
    for (int l = 0; l < 3; ++l) {
        mlp_mfma<256, 4>(w_bf + ((size_t)l * 64 + m) * 65536, X, wave, lane, acc);
        __syncthreads();
        mlp_write(b_ + ((size_t)l * 64 + m) * 256, X, wave, lane, acc);
        __syncthreads();
    }

    // final layer (I=2, rows 0..127 of padded wf), store G to global
    {
        floatx4 acf[2][4];
        mlp_mfma<256, 2>(wf_bf + (size_t)m * 32768, X, wave, lane, acf);
        const int quad = lane >> 4, l16 = lane & 15;
        const float* bm = bf_ + (size_t)m * 65;
        unsigned short* Gg = Gflat + (size_t)b0 * 4352 + m * 68;
        #pragma unroll
        for (int i = 0; i < 2; ++i) {
            const int rb = wave * 32 + i * 16 + quad * 4;
            if (rb < 68) {
                float bv[4];
                #pragma unroll
                for (int rr = 0; rr < 4; ++rr)
                    bv[rr] = (rb + rr < 65) ? bm[rb + rr] : 0.0f;
                #pragma unroll
                for (int j = 0; j < 4; ++j) {
                    const int cb = j * 16 + l16;
                    ushort4v o;
                    #pragma unroll
                    for (int rr = 0; rr < 4; ++rr)
                        o[rr] = f2bf(sigm(acf[i][j][rr] + bv[rr]));
                    *(ushort4v*)&Gg[(size_t)cb * 4352 + rb] = o;
                }
            }
        }
    }
}

// ---- contraction: P[kc][n][b] = sum_{k in chunk} XW[n][k] G[b][k]; K=4352, kc x2 ----
// grid 512 (XCD-swizzled, n-colocated), 512 thr = 8 waves, tile 128n x 128b,
// wave tile 64x32. A (XW) fragments straight from global/L2; B (G) staged in LDS.
__global__ __launch_bounds__(512, 4)
void contract_gemm(const unsigned short* __restrict__ XW,
                   const unsigned short* __restrict__ G,
                   float* __restrict__ P) {
    const int bid  = blockIdx.x;
    const int xcd  = bid & 7, slot = bid >> 3;       // slot 0..63
    const int r0 = (xcd * 4 + (slot & 3)) << 7;      // n-tile (XCD-colocated)
    const int combo = slot >> 2;                     // 0..15
    const int c0 = (combo & 7) << 7;                 // b-tile
    const int kc = combo >> 3;                       // 0..1
    const int kb = kc * 2176;
    float* Pc = P + (size_t)kc * 4096 * 1024;

    __shared__ unsigned short Bs[128 * 64];          // 16 KB

    const int tid = threadIdx.x;
    const int wave = tid >> 6, lane = tid & 63;
    const int quad = lane >> 4, l16 = lane & 15;
    const int wr = (wave & 1) * 64;                  // n offset in tile
    const int wc = (wave >> 1) * 32;                 // b offset in tile

    const int srow = wave * 8 + (lane >> 3);         // staging row (round t adds 64)
    const int spos = lane & 7;

    const unsigned short* Arow[4];
    #pragma unroll
    for (int i = 0; i < 4; ++i)
        Arow[i] = XW + (size_t)(r0 + wr + i * 16 + l16) * 4352 + kb;

    floatx4 acc[4][2];
    const floatx4 zero = {0.f, 0.f, 0.f, 0.f};
    #pragma unroll
    for (int i = 0; i < 4; ++i)
        #pragma unroll
        for (int j = 0; j < 2; ++j) acc[i][j] = zero;

    for (int k0 = 0; k0 < 2176; k0 += 64) {
        // stage B tile: 128 rows x 64 shorts, 2 rounds of 512 lanes
        #pragma unroll
        for (int t = 0; t < 2; ++t) {
            const int row = srow + t * 64;
            const int fc  = spos ^ (row & 7);
            load_lds16(G + (size_t)(c0 + row) * 4352 + kb + k0 + fc * 8,
                       &Bs[(t * 64 + wave * 8) * 64]);
        }
        // A fragments from global (issued before barrier -> overlap the drain)
        short8 af[2][4];
        #pragma unroll
        for (int kk = 0; kk < 2; ++kk)
            #pragma unroll
            for (int i = 0; i < 4; ++i)
                af[kk][i] = *(const short8*)(Arow[i] + k0 + kk * 32 + quad * 8);
        __syncthreads();

        #pragma unroll
        for (int kk = 0; kk < 2; ++kk) {
            short8 bf[2];
            #pragma unroll
            for (int j = 0; j < 2; ++j) {
                const int cb = wc + j * 16 + l16;
                bf[j] = *(const short8*)&Bs[cb * 64 + (((kk * 4 + quad) ^ (cb & 7)) * 8)];
            }
            #pragma unroll
            for (int i = 0; i < 4; ++i)
                #pragma unroll
                for (int j = 0; j < 2; ++j)
                    acc[i][j] = __builtin_amdgcn_mfma_f32_16x16x32_bf16(af[kk][i], bf[j], acc[i][j], 0, 0, 0);
        }
        __syncthreads();
    }

    #pragma unroll
    for (int i = 0; i < 4; ++i) {
        const int rb = r0 + wr + i * 16 + quad * 4;
        #pragma unroll
        for (int rr = 0; rr < 4; ++rr)
            #pragma unroll
            for (int j = 0; j < 2; ++j) {
                const int col = c0 + wc + j * 16 + l16;
                Pc[(size_t)(rb + rr) * 1024 + col] = acc[i][j][rr];
            }
    }
}

// ---- final reduce of 2 K-partials ----
__global__ void reduce2(const float* __restrict__ P, float* __restrict__ out) {
    const int i = blockIdx.x * 256 + threadIdx.x;    // per float4, 1048576 total
    const float4* p = (const float4*)P;
    float4 a = p[i], b = p[i + 1048576];
    ((float4*)out)[i] = (float4){ a.x + b.x, a.y + b.y, a.z + b.z, a.w + b.w };
}

extern "C" void kernel_launch(void* const* d_in, const int* in_sizes, int n_in,
                              void* d_out, int out_size, void* d_ws, size_t ws_size,
                              hipStream_t stream) {
    const float* u   = (const float*)d_in[0];
    const float* w0  = (const float*)d_in[1];
    const float* b0_ = (const float*)d_in[2];
    const float* w   = (const float*)d_in[3];
    const float* b   = (const float*)d_in[4];
    const float* wf  = (const float*)d_in[5];
    const float* bf_ = (const float*)d_in[6];
    const float* xi  = (const float*)d_in[7];
    float* out = (float*)d_out;

    unsigned short* w0_bf = (unsigned short*)d_ws;             // 1,048,576
    unsigned short* w_bf  = w0_bf + 1048576;                   // 12,582,912
    unsigned short* wf_bf = w_bf  + 12582912;                  // 2,097,152
    unsigned short* Gflat = wf_bf + 2097152;                   // 4,456,448 (1024 x 4352)
    unsigned short* XW    = Gflat + 4456448;                   // 17,825,792 (4096 x 4352)
    float*          P     = (float*)(XW + 17825792);           // 2 x 4096 x 1024 fp32

    prep<<<17408, 256, 0, stream>>>(w0, w, wf, xi, w0_bf, w_bf, wf_bf, (unsigned int*)XW);
    fused_mlp<<<1024, 256, 0, stream>>>(u, w0_bf, b0_, w_bf, b, wf_bf, bf_, Gflat);
    contract_gemm<<<512, 512, 0, stream>>>(XW, Gflat, P);
    reduce2<<<4096, 256, 0, stream>>>(P, out);
}

// Round 6
// 359.895 us; speedup vs baseline: 1.2009x; 1.2009x over previous
//
#include <hip/hip_runtime.h>
#include <math.h>

typedef __attribute__((ext_vector_type(8))) short short8;
typedef __attribute__((ext_vector_type(4))) float floatx4;
typedef __attribute__((ext_vector_type(4))) unsigned short ushort4v;

__device__ __forceinline__ void load_lds16(const void* g, void* l) {
    __builtin_amdgcn_global_load_lds((const __attribute__((address_space(1))) void*)g,
                                     (__attribute__((address_space(3))) void*)l,
                                     16, 0, 0);
}

__device__ __forceinline__ unsigned short f2bf(float x) {
    union { float f; unsigned int u; } v; v.f = x;
    unsigned int r = v.u + 0x7fffu + ((v.u >> 16) & 1u);
    return (unsigned short)(r >> 16);
}

__device__ __forceinline__ float sigm(float x) { return 1.0f / (1.0f + __expf(-x)); }

// ---- fused prep: weight bf16 conversions + Toeplitz XW build ----
__global__ void prep(const float* __restrict__ w0, const float* __restrict__ w,
                     const float* __restrict__ wf, const float* __restrict__ xi,
                     unsigned short* __restrict__ w0d, unsigned short* __restrict__ wd,
                     unsigned short* __restrict__ wfd, unsigned int* __restrict__ xw) {
    const int bid = blockIdx.x;
    if (bid < 1024) {
        int i = bid * 256 + threadIdx.x;
        float4 v = ((const float4*)w0)[i];
        ((ushort4v*)w0d)[i] = (ushort4v){ f2bf(v.x), f2bf(v.y), f2bf(v.z), f2bf(v.w) };
    } else if (bid < 13312) {
        int i = (bid - 1024) * 256 + threadIdx.x;
        float4 v = ((const float4*)w)[i];
        ((ushort4v*)wd)[i] = (ushort4v){ f2bf(v.x), f2bf(v.y), f2bf(v.z), f2bf(v.w) };
    } else if (bid < 15360) {
        int idx = (bid - 13312) * 256 + threadIdx.x;
        int e = idx * 4;
        int m = e >> 15, r = (e >> 8) & 127, c = e & 255;
        ushort4v o = {0, 0, 0, 0};
        if (r < 65) {
            float4 v = *(const float4*)&wf[((size_t)m * 65 + r) * 256 + c];
            o = (ushort4v){ f2bf(v.x), f2bf(v.y), f2bf(v.z), f2bf(v.w) };
        }
        ((ushort4v*)wfd)[idx] = o;
    } else {
        const int k = bid - 15360;
        const int m = k >> 5;
        const int n0 = (k & 31) * 128;
        const float* xim = xi + (size_t)m * 4160;
        for (int t = 0; t < 17; ++t) {
            const int d = threadIdx.x * 17 + t;
            const int row = d / 34;
            const int pos = d - row * 34;
            const int n = n0 + row;
            const int j0 = pos * 2;
            const float v0 = (j0 < 65) ? xim[n + j0] : 0.0f;
            const float v1 = (j0 + 1 < 65) ? xim[n + j0 + 1] : 0.0f;
            xw[(size_t)n * 2176 + (size_t)m * 34 + pos] =
                (unsigned int)f2bf(v0) | ((unsigned int)f2bf(v1) << 16);
        }
    }
}

// ---- zero d_out (re-poisoned to 0xAA before every timed launch) ----
__global__ void zero_out(float4* __restrict__ out) {
    out[blockIdx.x * 256 + threadIdx.x] = (float4){0.f, 0.f, 0.f, 0.f};
}

// ---- one MLP layer: MFMA phase (weights from global/L2, X from LDS) ----
// X layout: X[b][k] at b*K + ((k/8) ^ (b&7))*8 + (k&7)   (shorts)
template<int K, int I>
__device__ __forceinline__ void mlp_mfma(
    const unsigned short* __restrict__ Wm, const unsigned short* src,
    int wave, int lane, floatx4 (*acc)[4])
{
    const int quad = lane >> 4, l16 = lane & 15;
    const int rbw = wave * (I * 16);
    const floatx4 zero = {0.f, 0.f, 0.f, 0.f};
    #pragma unroll
    for (int i = 0; i < I; ++i)
        #pragma unroll
        for (int j = 0; j < 4; ++j) acc[i][j] = zero;

    short8 af[I];
    #pragma unroll
    for (int i = 0; i < I; ++i)
        af[i] = *(const short8*)&Wm[(size_t)(rbw + i * 16 + l16) * K + quad * 8];

    #pragma unroll
    for (int kk = 0; kk < K / 32; ++kk) {
        short8 afn[I];
        if (kk + 1 < K / 32) {
            #pragma unroll
            for (int i = 0; i < I; ++i)
                afn[i] = *(const short8*)&Wm[(size_t)(rbw + i * 16 + l16) * K + (kk + 1) * 32 + quad * 8];
        }
        short8 bf[4];
        #pragma unroll
        for (int j = 0; j < 4; ++j) {
            const int cb = j * 16 + l16;
            bf[j] = *(const short8*)&src[cb * K + (((kk * 4 + quad) ^ (cb & 7)) * 8)];
        }
        #pragma unroll
        for (int i = 0; i < I; ++i)
            #pragma unroll
            for (int j = 0; j < 4; ++j)
                acc[i][j] = __builtin_amdgcn_mfma_f32_16x16x32_bf16(af[i], bf[j], acc[i][j], 0, 0, 0);
        #pragma unroll
        for (int i = 0; i < I; ++i) af[i] = afn[i];
    }
}

// epilogue: bias+sigmoid+bf16, in-place into the same X buffer (K_out=256 layout)
__device__ __forceinline__ void mlp_write(
    const float* __restrict__ bm, unsigned short* dst,
    int wave, int lane, floatx4 (*acc)[4])
{
    const int quad = lane >> 4, l16 = lane & 15;
    const int rbw = wave * 64;
    #pragma unroll
    for (int i = 0; i < 4; ++i) {
        const int rb = rbw + i * 16 + quad * 4;
        float bv0 = bm[rb], bv1 = bm[rb + 1], bv2 = bm[rb + 2], bv3 = bm[rb + 3];
        #pragma unroll
        for (int j = 0; j < 4; ++j) {
            const int cb = j * 16 + l16;
            ushort4v o;
            o[0] = f2bf(sigm(acc[i][j][0] + bv0));
            o[1] = f2bf(sigm(acc[i][j][1] + bv1));
            o[2] = f2bf(sigm(acc[i][j][2] + bv2));
            o[3] = f2bf(sigm(acc[i][j][3] + bv3));
            *(ushort4v*)&dst[cb * 256 + (((rb >> 3) ^ (cb & 7)) * 8) + (rb & 7)] = o;
        }
    }
}

// ---- fused MLP: 5 layers, single 32 KB in-place activation buffer ----
// grid 1024 = 64 m x 16 batch-tiles (XCD-swizzled), 256 threads.
// launch_bounds(256,3): 170-reg cap (no spill; kernel needs ~130), 3 blocks/CU.
__global__ __launch_bounds__(256, 3)
void fused_mlp(const float* __restrict__ u,
               const unsigned short* __restrict__ w0_bf, const float* __restrict__ b0_,
               const unsigned short* __restrict__ w_bf,  const float* __restrict__ b_,
               const unsigned short* __restrict__ wf_bf, const float* __restrict__ bf_,
               unsigned short* __restrict__ Gflat) {
    __shared__ unsigned short X[64 * 256];   // 32 KB

    const int bid = blockIdx.x;
    const int xcd = bid & 7, slot = bid >> 3;
    const int m  = (xcd << 3) + (slot >> 4);
    const int b0 = (slot & 15) << 6;
    const int tid = threadIdx.x, wave = tid >> 6, lane = tid & 63;

    // stage u (fp32) -> X (bf16, K=64 layout)
    {
        const int b = tid >> 2, dc = tid & 3;
        const float* up = u + (size_t)(b0 + b) * 64 + dc * 16;
        float4 v0 = *(const float4*)(up);
        float4 v1 = *(const float4*)(up + 4);
        float4 v2 = *(const float4*)(up + 8);
        float4 v3 = *(const float4*)(up + 12);
        short8 c0 = { (short)f2bf(v0.x), (short)f2bf(v0.y), (short)f2bf(v0.z), (short)f2bf(v0.w),
                      (short)f2bf(v1.x), (short)f2bf(v1.y), (short)f2bf(v1.z), (short)f2bf(v1.w) };
        short8 c1 = { (short)f2bf(v2.x), (short)f2bf(v2.y), (short)f2bf(v2.z), (short)f2bf(v2.w),
                      (short)f2bf(v3.x), (short)f2bf(v3.y), (short)f2bf(v3.z), (short)f2bf(v3.w) };
        *(short8*)&X[b * 64 + (((dc * 2)     ^ (b & 7)) * 8)] = c0;
        *(short8*)&X[b * 64 + (((dc * 2 + 1) ^ (b & 7)) * 8)] = c1;
    }
    __syncthreads();

    floatx4 acc[4][4];

    mlp_mfma<64, 4>(w0_bf + (size_t)m * 16384, X, wave, lane, acc);
    __syncthreads();
    mlp_write(b0_ + (size_t)m * 256, X, wave, lane, acc);
    __syncthreads();

    #pragma unroll 1
    for (int l = 0; l < 3; ++l) {
        mlp_mfma<256, 4>(w_bf + ((size_t)l * 64 + m) * 65536, X, wave, lane, acc);
        __syncthreads();
        mlp_write(b_ + ((size_t)l * 64 + m) * 256, X, wave, lane, acc);
        __syncthreads();
    }

    {
        floatx4 acf[2][4];
        mlp_mfma<256, 2>(wf_bf + (size_t)m * 32768, X, wave, lane, acf);
        const int quad = lane >> 4, l16 = lane & 15;
        const float* bm = bf_ + (size_t)m * 65;
        unsigned short* Gg = Gflat + (size_t)b0 * 4352 + m * 68;
        #pragma unroll
        for (int i = 0; i < 2; ++i) {
            const int rb = wave * 32 + i * 16 + quad * 4;
            if (rb < 68) {
                float bv[4];
                #pragma unroll
                for (int rr = 0; rr < 4; ++rr)
                    bv[rr] = (rb + rr < 65) ? bm[rb + rr] : 0.0f;
                #pragma unroll
                for (int j = 0; j < 4; ++j) {
                    const int cb = j * 16 + l16;
                    ushort4v o;
                    #pragma unroll
                    for (int rr = 0; rr < 4; ++rr)
                        o[rr] = f2bf(sigm(acf[i][j][rr] + bv[rr]));
                    *(ushort4v*)&Gg[(size_t)cb * 4352 + rb] = o;
                }
            }
        }
    }
}

// ---- contraction: out[n][b] += sum_{k in chunk} XW[n][k] G[b][k]; K=4352, kc x4 ----
// Both operands staged via global_load_lds (R2 pattern). grid 1024, 256 thr,
// 128x128 tile, BK=64, 4 blocks/CU target. Epilogue: fp32 atomicAdd into out.
__global__ __launch_bounds__(256, 3)
void contract_gemm(const unsigned short* __restrict__ XW,
                   const unsigned short* __restrict__ G,
                   float* __restrict__ out) {
    const int bid = blockIdx.x;
    const int xcd = bid & 7, slot = bid >> 3;          // 0..127
    const int kc  = slot >> 5;                          // 0..3
    const int rst = slot & 31;
    const int r0 = ((xcd << 2) + (rst >> 3)) << 7;      // n-tile (XCD-colocated)
    const int c0 = (rst & 7) << 7;                      // b-tile
    const int kb = kc * 1088;

    __shared__ unsigned short As[128 * 64];
    __shared__ unsigned short Bs[128 * 64];

    const int tid = threadIdx.x;
    const int wave = tid >> 6, lane = tid & 63;
    const int quad = lane >> 4, l16 = lane & 15;
    const int wr = (wave & 1) * 64;
    const int wc = (wave >> 1) * 64;
    const int srow = wave * 32 + (lane >> 3);
    const int spos = lane & 7;

    floatx4 acc[4][4];
    const floatx4 zero = {0.f, 0.f, 0.f, 0.f};
    #pragma unroll
    for (int i = 0; i < 4; ++i)
        #pragma unroll
        for (int j = 0; j < 4; ++j) acc[i][j] = zero;

    for (int k0 = kb; k0 < kb + 1088; k0 += 64) {
        #pragma unroll
        for (int t = 0; t < 4; ++t) {
            const int row = srow + t * 8;
            const int fc  = spos ^ (row & 7);
            load_lds16(XW + (size_t)(r0 + row) * 4352 + k0 + fc * 8,
                       &As[(wave * 32 + t * 8) * 64]);
            load_lds16(G + (size_t)(c0 + row) * 4352 + k0 + fc * 8,
                       &Bs[(wave * 32 + t * 8) * 64]);
        }
        __syncthreads();

        #pragma unroll
        for (int kk = 0; kk < 2; ++kk) {
            short8 af[4], bfr[4];
            #pragma unroll
            for (int i = 0; i < 4; ++i) {
                const int ra = wr + i * 16 + l16;
                af[i]  = *(const short8*)&As[ra * 64 + (((kk * 4 + quad) ^ (ra & 7)) * 8)];
                const int cb = wc + i * 16 + l16;
                bfr[i] = *(const short8*)&Bs[cb * 64 + (((kk * 4 + quad) ^ (cb & 7)) * 8)];
            }
            #pragma unroll
            for (int i = 0; i < 4; ++i)
                #pragma unroll
                for (int j = 0; j < 4; ++j)
                    acc[i][j] = __builtin_amdgcn_mfma_f32_16x16x32_bf16(af[i], bfr[j], acc[i][j], 0, 0, 0);
        }
        __syncthreads();
    }

    #pragma unroll
    for (int i = 0; i < 4; ++i) {
        const int rb = r0 + wr + i * 16 + quad * 4;
        #pragma unroll
        for (int rr = 0; rr < 4; ++rr)
            #pragma unroll
            for (int j = 0; j < 4; ++j) {
                const int col = c0 + wc + j * 16 + l16;
                atomicAdd(&out[(size_t)(rb + rr) * 1024 + col], acc[i][j][rr]);
            }
    }
}

extern "C" void kernel_launch(void* const* d_in, const int* in_sizes, int n_in,
                              void* d_out, int out_size, void* d_ws, size_t ws_size,
                              hipStream_t stream) {
    const float* u   = (const float*)d_in[0];
    const float* w0  = (const float*)d_in[1];
    const float* b0_ = (const float*)d_in[2];
    const float* w   = (const float*)d_in[3];
    const float* b   = (const float*)d_in[4];
    const float* wf  = (const float*)d_in[5];
    const float* bf_ = (const float*)d_in[6];
    const float* xi  = (const float*)d_in[7];
    float* out = (float*)d_out;

    unsigned short* w0_bf = (unsigned short*)d_ws;             // 1,048,576
    unsigned short* w_bf  = w0_bf + 1048576;                   // 12,582,912
    unsigned short* wf_bf = w_bf  + 12582912;                  // 2,097,152
    unsigned short* Gflat = wf_bf + 2097152;                   // 4,456,448 (1024 x 4352)
    unsigned short* XW    = Gflat + 4456448;                   // 17,825,792 (4096 x 4352)

    prep<<<17408, 256, 0, stream>>>(w0, w, wf, xi, w0_bf, w_bf, wf_bf, (unsigned int*)XW);
    zero_out<<<4096, 256, 0, stream>>>((float4*)out);
    fused_mlp<<<1024, 256, 0, stream>>>(u, w0_bf, b0_, w_bf, b, wf_bf, bf_, Gflat);
    contract_gemm<<<1024, 256, 0, stream>>>(XW, Gflat, out);
}

// Round 7
// 318.816 us; speedup vs baseline: 1.3557x; 1.1288x over previous
//
#include <hip/hip_runtime.h>
#include <math.h>

typedef __attribute__((ext_vector_type(8))) short short8;
typedef __attribute__((ext_vector_type(4))) float floatx4;
typedef __attribute__((ext_vector_type(4))) unsigned short ushort4v;

__device__ __forceinline__ void load_lds16(const void* g, void* l) {
    __builtin_amdgcn_global_load_lds((const __attribute__((address_space(1))) void*)g,
                                     (__attribute__((address_space(3))) void*)l,
                                     16, 0, 0);
}

__device__ __forceinline__ unsigned short f2bf(float x) {
    union { float f; unsigned int u; } v; v.f = x;
    unsigned int r = v.u + 0x7fffu + ((v.u >> 16) & 1u);
    return (unsigned short)(r >> 16);
}

__device__ __forceinline__ float sigm(float x) { return 1.0f / (1.0f + __expf(-x)); }

// ---- fused prep: weight bf16 conversions + Toeplitz XW build ----
__global__ void prep(const float* __restrict__ w0, const float* __restrict__ w,
                     const float* __restrict__ wf, const float* __restrict__ xi,
                     unsigned short* __restrict__ w0d, unsigned short* __restrict__ wd,
                     unsigned short* __restrict__ wfd, unsigned int* __restrict__ xw) {
    const int bid = blockIdx.x;
    if (bid < 1024) {
        int i = bid * 256 + threadIdx.x;
        float4 v = ((const float4*)w0)[i];
        ((ushort4v*)w0d)[i] = (ushort4v){ f2bf(v.x), f2bf(v.y), f2bf(v.z), f2bf(v.w) };
    } else if (bid < 13312) {
        int i = (bid - 1024) * 256 + threadIdx.x;
        float4 v = ((const float4*)w)[i];
        ((ushort4v*)wd)[i] = (ushort4v){ f2bf(v.x), f2bf(v.y), f2bf(v.z), f2bf(v.w) };
    } else if (bid < 15360) {
        int idx = (bid - 13312) * 256 + threadIdx.x;
        int e = idx * 4;
        int m = e >> 15, r = (e >> 8) & 127, c = e & 255;
        ushort4v o = {0, 0, 0, 0};
        if (r < 65) {
            float4 v = *(const float4*)&wf[((size_t)m * 65 + r) * 256 + c];
            o = (ushort4v){ f2bf(v.x), f2bf(v.y), f2bf(v.z), f2bf(v.w) };
        }
        ((ushort4v*)wfd)[idx] = o;
    } else {
        const int k = bid - 15360;
        const int m = k >> 5;
        const int n0 = (k & 31) * 128;
        const float* xim = xi + (size_t)m * 4160;
        for (int t = 0; t < 17; ++t) {
            const int d = threadIdx.x * 17 + t;
            const int row = d / 34;
            const int pos = d - row * 34;
            const int n = n0 + row;
            const int j0 = pos * 2;
            const float v0 = (j0 < 65) ? xim[n + j0] : 0.0f;
            const float v1 = (j0 + 1 < 65) ? xim[n + j0 + 1] : 0.0f;
            xw[(size_t)n * 2176 + (size_t)m * 34 + pos] =
                (unsigned int)f2bf(v0) | ((unsigned int)f2bf(v1) << 16);
        }
    }
}

// ---- one MLP layer: MFMA phase (weights from global/L2, X from LDS) ----
// X layout: X[b][k] at b*K + ((k/8) ^ (b&7))*8 + (k&7)   (shorts)
// NO register prefetch of next-kk weights: +32 VGPRs caused scratch spill (R5).
template<int K, int I>
__device__ __forceinline__ void mlp_mfma(
    const unsigned short* __restrict__ Wm, const unsigned short* src,
    int wave, int lane, floatx4 (*acc)[4])
{
    const int quad = lane >> 4, l16 = lane & 15;
    const int rbw = wave * (I * 16);
    const floatx4 zero = {0.f, 0.f, 0.f, 0.f};
    #pragma unroll
    for (int i = 0; i < I; ++i)
        #pragma unroll
        for (int j = 0; j < 4; ++j) acc[i][j] = zero;

    #pragma unroll
    for (int kk = 0; kk < K / 32; ++kk) {
        short8 af[I], bf[4];
        #pragma unroll
        for (int i = 0; i < I; ++i)
            af[i] = *(const short8*)&Wm[(size_t)(rbw + i * 16 + l16) * K + kk * 32 + quad * 8];
        #pragma unroll
        for (int j = 0; j < 4; ++j) {
            const int cb = j * 16 + l16;
            bf[j] = *(const short8*)&src[cb * K + (((kk * 4 + quad) ^ (cb & 7)) * 8)];
        }
        #pragma unroll
        for (int i = 0; i < I; ++i)
            #pragma unroll
            for (int j = 0; j < 4; ++j)
                acc[i][j] = __builtin_amdgcn_mfma_f32_16x16x32_bf16(af[i], bf[j], acc[i][j], 0, 0, 0);
    }
}

// epilogue: bias+sigmoid+bf16, in-place into the same X buffer (K_out=256 layout)
__device__ __forceinline__ void mlp_write(
    const float* __restrict__ bm, unsigned short* dst,
    int wave, int lane, floatx4 (*acc)[4])
{
    const int quad = lane >> 4, l16 = lane & 15;
    const int rbw = wave * 64;
    #pragma unroll
    for (int i = 0; i < 4; ++i) {
        const int rb = rbw + i * 16 + quad * 4;
        float bv0 = bm[rb], bv1 = bm[rb + 1], bv2 = bm[rb + 2], bv3 = bm[rb + 3];
        #pragma unroll
        for (int j = 0; j < 4; ++j) {
            const int cb = j * 16 + l16;
            ushort4v o;
            o[0] = f2bf(sigm(acc[i][j][0] + bv0));
            o[1] = f2bf(sigm(acc[i][j][1] + bv1));
            o[2] = f2bf(sigm(acc[i][j][2] + bv2));
            o[3] = f2bf(sigm(acc[i][j][3] + bv3));
            *(ushort4v*)&dst[cb * 256 + (((rb >> 3) ^ (cb & 7)) * 8) + (rb & 7)] = o;
        }
    }
}

// ---- fused MLP: 5 layers, single 32 KB in-place activation buffer ----
// grid 1024 = 64 m x 16 batch-tiles (XCD-swizzled), 256 threads, 3 blocks/CU.
__global__ __launch_bounds__(256, 3)
void fused_mlp(const float* __restrict__ u,
               const unsigned short* __restrict__ w0_bf, const float* __restrict__ b0_,
               const unsigned short* __restrict__ w_bf,  const float* __restrict__ b_,
               const unsigned short* __restrict__ wf_bf, const float* __restrict__ bf_,
               unsigned short* __restrict__ Gflat) {
    __shared__ unsigned short X[64 * 256];   // 32 KB

    const int bid = blockIdx.x;
    const int xcd = bid & 7, slot = bid >> 3;
    const int m  = (xcd << 3) + (slot >> 4);
    const int b0 = (slot & 15) << 6;
    const int tid = threadIdx.x, wave = tid >> 6, lane = tid & 63;

    // stage u (fp32) -> X (bf16, K=64 layout)
    {
        const int b = tid >> 2, dc = tid & 3;
        const float* up = u + (size_t)(b0 + b) * 64 + dc * 16;
        float4 v0 = *(const float4*)(up);
        float4 v1 = *(const float4*)(up + 4);
        float4 v2 = *(const float4*)(up + 8);
        float4 v3 = *(const float4*)(up + 12);
        short8 c0 = { (short)f2bf(v0.x), (short)f2bf(v0.y), (short)f2bf(v0.z), (short)f2bf(v0.w),
                      (short)f2bf(v1.x), (short)f2bf(v1.y), (short)f2bf(v1.z), (short)f2bf(v1.w) };
        short8 c1 = { (short)f2bf(v2.x), (short)f2bf(v2.y), (short)f2bf(v2.z), (short)f2bf(v2.w),
                      (short)f2bf(v3.x), (short)f2bf(v3.y), (short)f2bf(v3.z), (short)f2bf(v3.w) };
        *(short8*)&X[b * 64 + (((dc * 2)     ^ (b & 7)) * 8)] = c0;
        *(short8*)&X[b * 64 + (((dc * 2 + 1) ^ (b & 7)) * 8)] = c1;
    }
    __syncthreads();

    floatx4 acc[4][4];

    mlp_mfma<64, 4>(w0_bf + (size_t)m * 16384, X, wave, lane, acc);
    __syncthreads();
    mlp_write(b0_ + (size_t)m * 256, X, wave, lane, acc);
    __syncthreads();

    #pragma unroll 1
    for (int l = 0; l < 3; ++l) {
        mlp_mfma<256, 4>(w_bf + ((size_t)l * 64 + m) * 65536, X, wave, lane, acc);
        __syncthreads();
        mlp_write(b_ + ((size_t)l * 64 + m) * 256, X, wave, lane, acc);
        __syncthreads();
    }

    {
        floatx4 acf[2][4];
        mlp_mfma<256, 2>(wf_bf + (size_t)m * 32768, X, wave, lane, acf);
        const int quad = lane >> 4, l16 = lane & 15;
        const float* bm = bf_ + (size_t)m * 65;
        unsigned short* Gg = Gflat + (size_t)b0 * 4352 + m * 68;
        #pragma unroll
        for (int i = 0; i < 2; ++i) {
            const int rb = wave * 32 + i * 16 + quad * 4;
            if (rb < 68) {
                float bv[4];
                #pragma unroll
                for (int rr = 0; rr < 4; ++rr)
                    bv[rr] = (rb + rr < 65) ? bm[rb + rr] : 0.0f;
                #pragma unroll
                for (int j = 0; j < 4; ++j) {
                    const int cb = j * 16 + l16;
                    ushort4v o;
                    #pragma unroll
                    for (int rr = 0; rr < 4; ++rr)
                        o[rr] = f2bf(sigm(acf[i][j][rr] + bv[rr]));
                    *(ushort4v*)&Gg[(size_t)cb * 4352 + rb] = o;
                }
            }
        }
    }
}

// ---- contraction: P[kc][n][b] = sum_{k in chunk} XW[n][k] G[b][k]; kc x2 ----
// Both operands via global_load_lds (R2 pattern). 512 thr = 8 waves,
// 128x128 tile, wave tile 64x32, BK=64. grid 512 = 2 blocks/CU.
__global__ __launch_bounds__(512, 2)
void contract_gemm(const unsigned short* __restrict__ XW,
                   const unsigned short* __restrict__ G,
                   float* __restrict__ P) {
    const int bid  = blockIdx.x;
    const int xcd  = bid & 7, slot = bid >> 3;       // 0..63
    const int r0 = ((xcd << 2) + (slot & 3)) << 7;   // n-tile (XCD-colocated)
    const int combo = slot >> 2;                     // 0..15
    const int c0 = (combo & 7) << 7;                 // b-tile
    const int kc = combo >> 3;                       // 0..1
    const int kb = kc * 2176;
    float* Pc = P + (size_t)kc * 4096 * 1024;

    __shared__ unsigned short As[128 * 64];
    __shared__ unsigned short Bs[128 * 64];

    const int tid = threadIdx.x;
    const int wave = tid >> 6, lane = tid & 63;
    const int quad = lane >> 4, l16 = lane & 15;
    const int wr = (wave & 1) * 64;
    const int wc = (wave >> 1) * 32;
    const int srow = wave * 16 + (lane >> 3);
    const int spos = lane & 7;

    floatx4 acc[4][2];
    const floatx4 zero = {0.f, 0.f, 0.f, 0.f};
    #pragma unroll
    for (int i = 0; i < 4; ++i)
        #pragma unroll
        for (int j = 0; j < 2; ++j) acc[i][j] = zero;

    for (int k0 = 0; k0 < 2176; k0 += 64) {
        #pragma unroll
        for (int t = 0; t < 2; ++t) {
            const int row = srow + t * 8;
            const int fc  = spos ^ (row & 7);
            load_lds16(XW + (size_t)(r0 + row) * 4352 + kb + k0 + fc * 8,
                       &As[(wave * 16 + t * 8) * 64]);
            load_lds16(G + (size_t)(c0 + row) * 4352 + kb + k0 + fc * 8,
                       &Bs[(wave * 16 + t * 8) * 64]);
        }
        __syncthreads();

        #pragma unroll
        for (int kk = 0; kk < 2; ++kk) {
            short8 af[4], bfr[2];
            #pragma unroll
            for (int i = 0; i < 4; ++i) {
                const int ra = wr + i * 16 + l16;
                af[i] = *(const short8*)&As[ra * 64 + (((kk * 4 + quad) ^ (ra & 7)) * 8)];
            }
            #pragma unroll
            for (int j = 0; j < 2; ++j) {
                const int cb = wc + j * 16 + l16;
                bfr[j] = *(const short8*)&Bs[cb * 64 + (((kk * 4 + quad) ^ (cb & 7)) * 8)];
            }
            #pragma unroll
            for (int i = 0; i < 4; ++i)
                #pragma unroll
                for (int j = 0; j < 2; ++j)
                    acc[i][j] = __builtin_amdgcn_mfma_f32_16x16x32_bf16(af[i], bfr[j], acc[i][j], 0, 0, 0);
        }
        __syncthreads();
    }

    #pragma unroll
    for (int i = 0; i < 4; ++i) {
        const int rb = r0 + wr + i * 16 + quad * 4;
        #pragma unroll
        for (int rr = 0; rr < 4; ++rr)
            #pragma unroll
            for (int j = 0; j < 2; ++j) {
                const int col = c0 + wc + j * 16 + l16;
                Pc[(size_t)(rb + rr) * 1024 + col] = acc[i][j][rr];
            }
    }
}

// ---- final reduce of 2 K-partials ----
__global__ void reduce2(const float* __restrict__ P, float* __restrict__ out) {
    const int i = blockIdx.x * 256 + threadIdx.x;
    const float4* p = (const float4*)P;
    float4 a = p[i], b = p[i + 1048576];
    ((float4*)out)[i] = (float4){ a.x + b.x, a.y + b.y, a.z + b.z, a.w + b.w };
}

extern "C" void kernel_launch(void* const* d_in, const int* in_sizes, int n_in,
                              void* d_out, int out_size, void* d_ws, size_t ws_size,
                              hipStream_t stream) {
    const float* u   = (const float*)d_in[0];
    const float* w0  = (const float*)d_in[1];
    const float* b0_ = (const float*)d_in[2];
    const float* w   = (const float*)d_in[3];
    const float* b   = (const float*)d_in[4];
    const float* wf  = (const float*)d_in[5];
    const float* bf_ = (const float*)d_in[6];
    const float* xi  = (const float*)d_in[7];
    float* out = (float*)d_out;

    unsigned short* w0_bf = (unsigned short*)d_ws;             // 1,048,576
    unsigned short* w_bf  = w0_bf + 1048576;                   // 12,582,912
    unsigned short* wf_bf = w_bf  + 12582912;                  // 2,097,152
    unsigned short* Gflat = wf_bf + 2097152;                   // 4,456,448 (1024 x 4352)
    unsigned short* XW    = Gflat + 4456448;                   // 17,825,792 (4096 x 4352)
    float*          P     = (float*)(XW + 17825792);           // 2 x 4096 x 1024 fp32

    prep<<<17408, 256, 0, stream>>>(w0, w, wf, xi, w0_bf, w_bf, wf_bf, (unsigned int*)XW);
    fused_mlp<<<1024, 256, 0, stream>>>(u, w0_bf, b0_, w_bf, b, wf_bf, bf_, Gflat);
    contract_gemm<<<512, 512, 0, stream>>>(XW, Gflat, P);
    reduce2<<<4096, 256, 0, stream>>>(P, out);
}

// Round 8
// 263.865 us; speedup vs baseline: 1.6380x; 1.2083x over previous
//
#include <hip/hip_runtime.h>
#include <math.h>

typedef __attribute__((ext_vector_type(8))) short short8;
typedef __attribute__((ext_vector_type(4))) float floatx4;
typedef __attribute__((ext_vector_type(4))) unsigned short ushort4v;

__device__ __forceinline__ void load_lds16(const void* g, void* l) {
    __builtin_amdgcn_global_load_lds((const __attribute__((address_space(1))) void*)g,
                                     (__attribute__((address_space(3))) void*)l,
                                     16, 0, 0);
}

__device__ __forceinline__ unsigned short f2bf(float x) {
    union { float f; unsigned int u; } v; v.f = x;
    unsigned int r = v.u + 0x7fffu + ((v.u >> 16) & 1u);
    return (unsigned short)(r >> 16);
}

__device__ __forceinline__ float sigm(float x) { return 1.0f / (1.0f + __expf(-x)); }

// ---- fused prep: weight bf16 conversions + Toeplitz XW build (coalesced) ----
// blocks: [0,1024) w0 | [1024,13312) w | [13312,15360) wf-pad | [15360,19456) XW rows
__global__ void prep(const float* __restrict__ w0, const float* __restrict__ w,
                     const float* __restrict__ wf, const float* __restrict__ xi,
                     unsigned short* __restrict__ w0d, unsigned short* __restrict__ wd,
                     unsigned short* __restrict__ wfd, unsigned int* __restrict__ xw) {
    const int bid = blockIdx.x;
    if (bid < 1024) {
        int i = bid * 256 + threadIdx.x;
        float4 v = ((const float4*)w0)[i];
        ((ushort4v*)w0d)[i] = (ushort4v){ f2bf(v.x), f2bf(v.y), f2bf(v.z), f2bf(v.w) };
    } else if (bid < 13312) {
        int i = (bid - 1024) * 256 + threadIdx.x;
        float4 v = ((const float4*)w)[i];
        ((ushort4v*)wd)[i] = (ushort4v){ f2bf(v.x), f2bf(v.y), f2bf(v.z), f2bf(v.w) };
    } else if (bid < 15360) {
        int idx = (bid - 13312) * 256 + threadIdx.x;
        int e = idx * 4;
        int m = e >> 15, r = (e >> 8) & 127, c = e & 255;
        ushort4v o = {0, 0, 0, 0};
        if (r < 65) {
            float4 v = *(const float4*)&wf[((size_t)m * 65 + r) * 256 + c];
            o = (ushort4v){ f2bf(v.x), f2bf(v.y), f2bf(v.z), f2bf(v.w) };
        }
        ((ushort4v*)wfd)[idx] = o;
    } else {
        // one block per output row n: writes 2176 CONSECUTIVE dwords (coalesced)
        const int n = bid - 15360;
        #pragma unroll
        for (int t = 0; t < 9; ++t) {
            const int idx = t * 256 + threadIdx.x;
            if (idx < 2176) {
                const int m = idx / 34;
                const int pos = idx - m * 34;
                const int j0 = pos * 2;
                const float* xim = xi + (size_t)m * 4160 + n;
                const float v0 = (j0 < 65) ? xim[j0] : 0.0f;
                const float v1 = (j0 + 1 < 65) ? xim[j0 + 1] : 0.0f;
                xw[(size_t)n * 2176 + idx] =
                    (unsigned int)f2bf(v0) | ((unsigned int)f2bf(v1) << 16);
            }
        }
    }
}

// ---- one MLP layer: MFMA phase (weights from global/L2, X from LDS) ----
// X layout: X[b][k] at b*K + ((k/8) ^ (b&7))*8 + (k&7)   (shorts)
// Register prefetch of next-kk weights — safe at launch_bounds(256,2) (cap 256).
template<int K, int I>
__device__ __forceinline__ void mlp_mfma(
    const unsigned short* __restrict__ Wm, const unsigned short* src,
    int wave, int lane, floatx4 (*acc)[4])
{
    const int quad = lane >> 4, l16 = lane & 15;
    const int rbw = wave * (I * 16);
    const floatx4 zero = {0.f, 0.f, 0.f, 0.f};
    #pragma unroll
    for (int i = 0; i < I; ++i)
        #pragma unroll
        for (int j = 0; j < 4; ++j) acc[i][j] = zero;

    short8 af[I];
    #pragma unroll
    for (int i = 0; i < I; ++i)
        af[i] = *(const short8*)&Wm[(size_t)(rbw + i * 16 + l16) * K + quad * 8];

    #pragma unroll
    for (int kk = 0; kk < K / 32; ++kk) {
        short8 afn[I];
        if (kk + 1 < K / 32) {
            #pragma unroll
            for (int i = 0; i < I; ++i)
                afn[i] = *(const short8*)&Wm[(size_t)(rbw + i * 16 + l16) * K + (kk + 1) * 32 + quad * 8];
        }
        short8 bf[4];
        #pragma unroll
        for (int j = 0; j < 4; ++j) {
            const int cb = j * 16 + l16;
            bf[j] = *(const short8*)&src[cb * K + (((kk * 4 + quad) ^ (cb & 7)) * 8)];
        }
        #pragma unroll
        for (int i = 0; i < I; ++i)
            #pragma unroll
            for (int j = 0; j < 4; ++j)
                acc[i][j] = __builtin_amdgcn_mfma_f32_16x16x32_bf16(af[i], bf[j], acc[i][j], 0, 0, 0);
        #pragma unroll
        for (int i = 0; i < I; ++i) af[i] = afn[i];
    }
}

// epilogue: bias+sigmoid+bf16, in-place into the same X buffer (K_out=256 layout)
__device__ __forceinline__ void mlp_write(
    const float* __restrict__ bm, unsigned short* dst,
    int wave, int lane, floatx4 (*acc)[4])
{
    const int quad = lane >> 4, l16 = lane & 15;
    const int rbw = wave * 64;
    #pragma unroll
    for (int i = 0; i < 4; ++i) {
        const int rb = rbw + i * 16 + quad * 4;
        float bv0 = bm[rb], bv1 = bm[rb + 1], bv2 = bm[rb + 2], bv3 = bm[rb + 3];
        #pragma unroll
        for (int j = 0; j < 4; ++j) {
            const int cb = j * 16 + l16;
            ushort4v o;
            o[0] = f2bf(sigm(acc[i][j][0] + bv0));
            o[1] = f2bf(sigm(acc[i][j][1] + bv1));
            o[2] = f2bf(sigm(acc[i][j][2] + bv2));
            o[3] = f2bf(sigm(acc[i][j][3] + bv3));
            *(ushort4v*)&dst[cb * 256 + (((rb >> 3) ^ (cb & 7)) * 8) + (rb & 7)] = o;
        }
    }
}

// ---- fused MLP: 5 layers, single 32 KB in-place activation buffer ----
// grid 1024 = 64 m x 16 batch-tiles (XCD-swizzled), 256 threads.
// (256,2): 256-reg cap — no spill with prefetch (~180 live).
__global__ __launch_bounds__(256, 2)
void fused_mlp(const float* __restrict__ u,
               const unsigned short* __restrict__ w0_bf, const float* __restrict__ b0_,
               const unsigned short* __restrict__ w_bf,  const float* __restrict__ b_,
               const unsigned short* __restrict__ wf_bf, const float* __restrict__ bf_,
               unsigned short* __restrict__ Gflat) {
    __shared__ unsigned short X[64 * 256];   // 32 KB

    const int bid = blockIdx.x;
    const int xcd = bid & 7, slot = bid >> 3;
    const int m  = (xcd << 3) + (slot >> 4);
    const int b0 = (slot & 15) << 6;
    const int tid = threadIdx.x, wave = tid >> 6, lane = tid & 63;

    // stage u (fp32) -> X (bf16, K=64 layout)
    {
        const int b = tid >> 2, dc = tid & 3;
        const float* up = u + (size_t)(b0 + b) * 64 + dc * 16;
        float4 v0 = *(const float4*)(up);
        float4 v1 = *(const float4*)(up + 4);
        float4 v2 = *(const float4*)(up + 8);
        float4 v3 = *(const float4*)(up + 12);
        short8 c0 = { (short)f2bf(v0.x), (short)f2bf(v0.y), (short)f2bf(v0.z), (short)f2bf(v0.w),
                      (short)f2bf(v1.x), (short)f2bf(v1.y), (short)f2bf(v1.z), (short)f2bf(v1.w) };
        short8 c1 = { (short)f2bf(v2.x), (short)f2bf(v2.y), (short)f2bf(v2.z), (short)f2bf(v2.w),
                      (short)f2bf(v3.x), (short)f2bf(v3.y), (short)f2bf(v3.z), (short)f2bf(v3.w) };
        *(short8*)&X[b * 64 + (((dc * 2)     ^ (b & 7)) * 8)] = c0;
        *(short8*)&X[b * 64 + (((dc * 2 + 1) ^ (b & 7)) * 8)] = c1;
    }
    __syncthreads();

    floatx4 acc[4][4];

    mlp_mfma<64, 4>(w0_bf + (size_t)m * 16384, X, wave, lane, acc);
    __syncthreads();
    mlp_write(b0_ + (size_t)m * 256, X, wave, lane, acc);
    __syncthreads();

    #pragma unroll 1
    for (int l = 0; l < 3; ++l) {
        mlp_mfma<256, 4>(w_bf + ((size_t)l * 64 + m) * 65536, X, wave, lane, acc);
        __syncthreads();
        mlp_write(b_ + ((size_t)l * 64 + m) * 256, X, wave, lane, acc);
        __syncthreads();
    }

    {
        floatx4 acf[2][4];
        mlp_mfma<256, 2>(wf_bf + (size_t)m * 32768, X, wave, lane, acf);
        const int quad = lane >> 4, l16 = lane & 15;
        const float* bm = bf_ + (size_t)m * 65;
        unsigned short* Gg = Gflat + (size_t)b0 * 4352 + m * 68;
        #pragma unroll
        for (int i = 0; i < 2; ++i) {
            const int rb = wave * 32 + i * 16 + quad * 4;
            if (rb < 68) {
                float bv[4];
                #pragma unroll
                for (int rr = 0; rr < 4; ++rr)
                    bv[rr] = (rb + rr < 65) ? bm[rb + rr] : 0.0f;
                #pragma unroll
                for (int j = 0; j < 4; ++j) {
                    const int cb = j * 16 + l16;
                    ushort4v o;
                    #pragma unroll
                    for (int rr = 0; rr < 4; ++rr)
                        o[rr] = f2bf(sigm(acf[i][j][rr] + bv[rr]));
                    *(ushort4v*)&Gg[(size_t)cb * 4352 + rb] = o;
                }
            }
        }
    }
}

// ---- contraction: P[kc][n][b] partials; K=4352, K-split x4, 256 thr, 128x128 ----
// grid 1024 (XCD-swizzled, n-colocated) -> 3-4 blocks/CU. Both operands via
// global_load_lds. (256,3): 170-reg cap, ~130 live, no spill.
__global__ __launch_bounds__(256, 3)
void contract_gemm(const unsigned short* __restrict__ XW,
                   const unsigned short* __restrict__ G,
                   float* __restrict__ P) {
    const int bid = blockIdx.x;
    const int xcd = bid & 7, slot = bid >> 3;          // 0..127
    const int kc  = slot >> 5;                          // 0..3
    const int rst = slot & 31;
    const int r0 = ((xcd << 2) + (rst >> 3)) << 7;      // n-tile (XCD-colocated)
    const int c0 = (rst & 7) << 7;                      // b-tile
    const int kb = kc * 1088;
    float* Pc = P + (size_t)kc * 4096 * 1024;

    __shared__ unsigned short As[128 * 64];
    __shared__ unsigned short Bs[128 * 64];

    const int tid = threadIdx.x;
    const int wave = tid >> 6, lane = tid & 63;
    const int quad = lane >> 4, l16 = lane & 15;
    const int wr = (wave & 1) * 64;
    const int wc = (wave >> 1) * 64;
    const int srow = wave * 32 + (lane >> 3);
    const int spos = lane & 7;

    floatx4 acc[4][4];
    const floatx4 zero = {0.f, 0.f, 0.f, 0.f};
    #pragma unroll
    for (int i = 0; i < 4; ++i)
        #pragma unroll
        for (int j = 0; j < 4; ++j) acc[i][j] = zero;

    for (int k0 = kb; k0 < kb + 1088; k0 += 64) {
        #pragma unroll
        for (int t = 0; t < 4; ++t) {
            const int row = srow + t * 8;
            const int fc  = spos ^ (row & 7);
            load_lds16(XW + (size_t)(r0 + row) * 4352 + k0 + fc * 8,
                       &As[(wave * 32 + t * 8) * 64]);
            load_lds16(G + (size_t)(c0 + row) * 4352 + k0 + fc * 8,
                       &Bs[(wave * 32 + t * 8) * 64]);
        }
        __syncthreads();

        #pragma unroll
        for (int kk = 0; kk < 2; ++kk) {
            short8 af[4], bfr[4];
            #pragma unroll
            for (int i = 0; i < 4; ++i) {
                const int ra = wr + i * 16 + l16;
                af[i]  = *(const short8*)&As[ra * 64 + (((kk * 4 + quad) ^ (ra & 7)) * 8)];
                const int cb = wc + i * 16 + l16;
                bfr[i] = *(const short8*)&Bs[cb * 64 + (((kk * 4 + quad) ^ (cb & 7)) * 8)];
            }
            #pragma unroll
            for (int i = 0; i < 4; ++i)
                #pragma unroll
                for (int j = 0; j < 4; ++j)
                    acc[i][j] = __builtin_amdgcn_mfma_f32_16x16x32_bf16(af[i], bfr[j], acc[i][j], 0, 0, 0);
        }
        __syncthreads();
    }

    #pragma unroll
    for (int i = 0; i < 4; ++i) {
        const int rb = r0 + wr + i * 16 + quad * 4;
        #pragma unroll
        for (int rr = 0; rr < 4; ++rr)
            #pragma unroll
            for (int j = 0; j < 4; ++j) {
                const int col = c0 + wc + j * 16 + l16;
                Pc[(size_t)(rb + rr) * 1024 + col] = acc[i][j][rr];
            }
    }
}

// ---- final reduce of 4 K-partials ----
__global__ void reduce4(const float* __restrict__ P, float* __restrict__ out) {
    const int i = blockIdx.x * 256 + threadIdx.x;
    const float4* p = (const float4*)P;
    float4 a = p[i], b = p[i + 1048576], c = p[i + 2097152], d = p[i + 3145728];
    ((float4*)out)[i] = (float4){ a.x + b.x + c.x + d.x, a.y + b.y + c.y + d.y,
                                  a.z + b.z + c.z + d.z, a.w + b.w + c.w + d.w };
}

extern "C" void kernel_launch(void* const* d_in, const int* in_sizes, int n_in,
                              void* d_out, int out_size, void* d_ws, size_t ws_size,
                              hipStream_t stream) {
    const float* u   = (const float*)d_in[0];
    const float* w0  = (const float*)d_in[1];
    const float* b0_ = (const float*)d_in[2];
    const float* w   = (const float*)d_in[3];
    const float* b   = (const float*)d_in[4];
    const float* wf  = (const float*)d_in[5];
    const float* bf_ = (const float*)d_in[6];
    const float* xi  = (const float*)d_in[7];
    float* out = (float*)d_out;

    unsigned short* w0_bf = (unsigned short*)d_ws;             // 1,048,576
    unsigned short* w_bf  = w0_bf + 1048576;                   // 12,582,912
    unsigned short* wf_bf = w_bf  + 12582912;                  // 2,097,152
    unsigned short* Gflat = wf_bf + 2097152;                   // 4,456,448 (1024 x 4352)
    unsigned short* XW    = Gflat + 4456448;                   // 17,825,792 (4096 x 4352)
    float*          P     = (float*)(XW + 17825792);           // 4 x 4096 x 1024 fp32

    prep<<<19456, 256, 0, stream>>>(w0, w, wf, xi, w0_bf, w_bf, wf_bf, (unsigned int*)XW);
    fused_mlp<<<1024, 256, 0, stream>>>(u, w0_bf, b0_, w_bf, b, wf_bf, bf_, Gflat);
    contract_gemm<<<1024, 256, 0, stream>>>(XW, Gflat, P);
    reduce4<<<4096, 256, 0, stream>>>(P, out);
}

// Round 9
// 262.589 us; speedup vs baseline: 1.6459x; 1.0049x over previous
//
#include <hip/hip_runtime.h>
#include <math.h>

typedef __attribute__((ext_vector_type(8))) short short8;
typedef __attribute__((ext_vector_type(4))) float floatx4;
typedef __attribute__((ext_vector_type(4))) unsigned short ushort4v;

__device__ __forceinline__ void load_lds16(const void* g, void* l) {
    __builtin_amdgcn_global_load_lds((const __attribute__((address_space(1))) void*)g,
                                     (__attribute__((address_space(3))) void*)l,
                                     16, 0, 0);
}

__device__ __forceinline__ unsigned short f2bf(float x) {
    union { float f; unsigned int u; } v; v.f = x;
    unsigned int r = v.u + 0x7fffu + ((v.u >> 16) & 1u);
    return (unsigned short)(r >> 16);
}

__device__ __forceinline__ float sigm(float x) { return 1.0f / (1.0f + __expf(-x)); }

// ---- prep: weights -> bf16 in MFMA-FRAGMENT ORDER + Toeplitz XW build ----
// Fragment order: chunk index within (m[,l]) = (rblk*Kk + kk)*64 + lane,
// chunk holds W[rblk*16 + (lane&15)][kk*32 + (lane>>4)*8 .. +8).
// A-fragment load in the MLP = base + lane*16B  (fully coalesced).
// blocks: [0,512) w0 | [512,6656) w | [6656,7680) wf-pad | [7680,11776) XW rows
__global__ void prep(const float* __restrict__ w0, const float* __restrict__ w,
                     const float* __restrict__ wf, const float* __restrict__ xi,
                     unsigned short* __restrict__ w0d, unsigned short* __restrict__ wd,
                     unsigned short* __restrict__ wfd, unsigned int* __restrict__ xw) {
    const int bid = blockIdx.x;
    if (bid < 6656) {
        // w0 (Kk=2, 2048 chunks/m) or w (Kk=8, 8192 chunks/(l,m))
        const bool is0 = bid < 512;
        const int c = (is0 ? bid : bid - 512) * 256 + threadIdx.x;
        const int cpm = is0 ? 2048 : 8192;      // chunks per matrix
        const int Kk  = is0 ? 2 : 8;
        const int K   = Kk * 32;
        const int mm  = c / cpm;                // m  (or l*64+m)
        const int cm  = c - mm * cpm;
        const int rblk = cm >> 6 >= 0 ? (cm / (Kk * 64)) : 0;
        const int rem  = cm - rblk * (Kk * 64);
        const int kk   = rem >> 6;
        const int lane = rem & 63;
        const int r  = rblk * 16 + (lane & 15);
        const int k0 = kk * 32 + (lane >> 4) * 8;
        const float* srcp = (is0 ? w0 : w) + ((size_t)mm * 256 + r) * K + k0;
        unsigned short* dstp = (is0 ? w0d : wd) + (size_t)c * 8;
        float4 a = *(const float4*)srcp;
        float4 b = *(const float4*)(srcp + 4);
        short8 o = { (short)f2bf(a.x), (short)f2bf(a.y), (short)f2bf(a.z), (short)f2bf(a.w),
                     (short)f2bf(b.x), (short)f2bf(b.y), (short)f2bf(b.z), (short)f2bf(b.w) };
        *(short8*)dstp = o;
    } else if (bid < 7680) {
        // wf: logical 128x256 (rows >=65 zero), Kk=8, 4096 chunks/m
        const int c = (bid - 6656) * 256 + threadIdx.x;
        const int m  = c >> 12;
        const int cm = c & 4095;
        const int rblk = cm >> 9;               // / (8*64)
        const int rem  = cm & 511;
        const int kk   = rem >> 6;
        const int lane = rem & 63;
        const int r  = rblk * 16 + (lane & 15);
        const int k0 = kk * 32 + (lane >> 4) * 8;
        short8 o = {0,0,0,0,0,0,0,0};
        if (r < 65) {
            const float* srcp = wf + ((size_t)m * 65 + r) * 256 + k0;
            float4 a = *(const float4*)srcp;
            float4 b = *(const float4*)(srcp + 4);
            o = (short8){ (short)f2bf(a.x), (short)f2bf(a.y), (short)f2bf(a.z), (short)f2bf(a.w),
                          (short)f2bf(b.x), (short)f2bf(b.y), (short)f2bf(b.z), (short)f2bf(b.w) };
        }
        *(short8*)(wfd + (size_t)c * 8) = o;
    } else {
        // XW row n: 2176 consecutive dwords (coalesced)
        const int n = bid - 7680;
        #pragma unroll
        for (int t = 0; t < 9; ++t) {
            const int idx = t * 256 + threadIdx.x;
            if (idx < 2176) {
                const int m = idx / 34;
                const int pos = idx - m * 34;
                const int j0 = pos * 2;
                const float* xim = xi + (size_t)m * 4160 + n;
                const float v0 = (j0 < 65) ? xim[j0] : 0.0f;
                const float v1 = (j0 + 1 < 65) ? xim[j0 + 1] : 0.0f;
                xw[(size_t)n * 2176 + idx] =
                    (unsigned int)f2bf(v0) | ((unsigned int)f2bf(v1) << 16);
            }
        }
    }
}

// ---- one MLP layer: weights from global in fragment order (coalesced), X in LDS ----
// X layout: X[b][k] at b*K + ((k/8) ^ (b&7))*8 + (k&7)   (shorts)
template<int K, int I>
__device__ __forceinline__ void mlp_mfma(
    const unsigned short* __restrict__ Wt, const unsigned short* src,
    int wave, int lane, floatx4 (*acc)[4])
{
    const int Kk = K / 32;
    const int quad = lane >> 4, l16 = lane & 15;
    const int rblk0 = wave * I;
    const floatx4 zero = {0.f, 0.f, 0.f, 0.f};
    #pragma unroll
    for (int i = 0; i < I; ++i)
        #pragma unroll
        for (int j = 0; j < 4; ++j) acc[i][j] = zero;

    short8 af[I];
    #pragma unroll
    for (int i = 0; i < I; ++i)
        af[i] = *(const short8*)&Wt[(size_t)(((rblk0 + i) * Kk + 0) * 64 + lane) * 8];

    #pragma unroll
    for (int kk = 0; kk < Kk; ++kk) {
        short8 afn[I];
        if (kk + 1 < Kk) {
            #pragma unroll
            for (int i = 0; i < I; ++i)
                afn[i] = *(const short8*)&Wt[(size_t)(((rblk0 + i) * Kk + kk + 1) * 64 + lane) * 8];
        }
        short8 bf[4];
        #pragma unroll
        for (int j = 0; j < 4; ++j) {
            const int cb = j * 16 + l16;
            bf[j] = *(const short8*)&src[cb * K + (((kk * 4 + quad) ^ (cb & 7)) * 8)];
        }
        #pragma unroll
        for (int i = 0; i < I; ++i)
            #pragma unroll
            for (int j = 0; j < 4; ++j)
                acc[i][j] = __builtin_amdgcn_mfma_f32_16x16x32_bf16(af[i], bf[j], acc[i][j], 0, 0, 0);
        #pragma unroll
        for (int i = 0; i < I; ++i) af[i] = afn[i];
    }
}

// epilogue: bias+sigmoid+bf16, in-place into the same X buffer (K_out=256 layout)
__device__ __forceinline__ void mlp_write(
    const float* __restrict__ bm, unsigned short* dst,
    int wave, int lane, floatx4 (*acc)[4])
{
    const int quad = lane >> 4, l16 = lane & 15;
    const int rbw = wave * 64;
    #pragma unroll
    for (int i = 0; i < 4; ++i) {
        const int rb = rbw + i * 16 + quad * 4;
        float bv0 = bm[rb], bv1 = bm[rb + 1], bv2 = bm[rb + 2], bv3 = bm[rb + 3];
        #pragma unroll
        for (int j = 0; j < 4; ++j) {
            const int cb = j * 16 + l16;
            ushort4v o;
            o[0] = f2bf(sigm(acc[i][j][0] + bv0));
            o[1] = f2bf(sigm(acc[i][j][1] + bv1));
            o[2] = f2bf(sigm(acc[i][j][2] + bv2));
            o[3] = f2bf(sigm(acc[i][j][3] + bv3));
            *(ushort4v*)&dst[cb * 256 + (((rb >> 3) ^ (cb & 7)) * 8) + (rb & 7)] = o;
        }
    }
}

// ---- fused MLP: 5 layers, single 32 KB in-place activation buffer ----
// grid 1024 = 64 m x 16 batch-tiles (XCD-swizzled), 256 threads, (256,2).
__global__ __launch_bounds__(256, 2)
void fused_mlp(const float* __restrict__ u,
               const unsigned short* __restrict__ w0_bf, const float* __restrict__ b0_,
               const unsigned short* __restrict__ w_bf,  const float* __restrict__ b_,
               const unsigned short* __restrict__ wf_bf, const float* __restrict__ bf_,
               unsigned short* __restrict__ Gflat) {
    __shared__ unsigned short X[64 * 256];   // 32 KB

    const int bid = blockIdx.x;
    const int xcd = bid & 7, slot = bid >> 3;
    const int m  = (xcd << 3) + (slot >> 4);
    const int b0 = (slot & 15) << 6;
    const int tid = threadIdx.x, wave = tid >> 6, lane = tid & 63;

    // stage u (fp32) -> X (bf16, K=64 layout)
    {
        const int b = tid >> 2, dc = tid & 3;
        const float* up = u + (size_t)(b0 + b) * 64 + dc * 16;
        float4 v0 = *(const float4*)(up);
        float4 v1 = *(const float4*)(up + 4);
        float4 v2 = *(const float4*)(up + 8);
        float4 v3 = *(const float4*)(up + 12);
        short8 c0 = { (short)f2bf(v0.x), (short)f2bf(v0.y), (short)f2bf(v0.z), (short)f2bf(v0.w),
                      (short)f2bf(v1.x), (short)f2bf(v1.y), (short)f2bf(v1.z), (short)f2bf(v1.w) };
        short8 c1 = { (short)f2bf(v2.x), (short)f2bf(v2.y), (short)f2bf(v2.z), (short)f2bf(v2.w),
                      (short)f2bf(v3.x), (short)f2bf(v3.y), (short)f2bf(v3.z), (short)f2bf(v3.w) };
        *(short8*)&X[b * 64 + (((dc * 2)     ^ (b & 7)) * 8)] = c0;
        *(short8*)&X[b * 64 + (((dc * 2 + 1) ^ (b & 7)) * 8)] = c1;
    }
    __syncthreads();

    floatx4 acc[4][4];

    mlp_mfma<64, 4>(w0_bf + (size_t)m * 16384, X, wave, lane, acc);
    __syncthreads();
    mlp_write(b0_ + (size_t)m * 256, X, wave, lane, acc);
    __syncthreads();

    #pragma unroll 1
    for (int l = 0; l < 3; ++l) {
        mlp_mfma<256, 4>(w_bf + ((size_t)l * 64 + m) * 65536, X, wave, lane, acc);
        __syncthreads();
        mlp_write(b_ + ((size_t)l * 64 + m) * 256, X, wave, lane, acc);
        __syncthreads();
    }

    {
        floatx4 acf[2][4];
        mlp_mfma<256, 2>(wf_bf + (size_t)m * 32768, X, wave, lane, acf);
        const int quad = lane >> 4, l16 = lane & 15;
        const float* bm = bf_ + (size_t)m * 65;
        unsigned short* Gg = Gflat + (size_t)b0 * 4352 + m * 68;
        #pragma unroll
        for (int i = 0; i < 2; ++i) {
            const int rb = wave * 32 + i * 16 + quad * 4;
            if (rb < 68) {
                float bv[4];
                #pragma unroll
                for (int rr = 0; rr < 4; ++rr)
                    bv[rr] = (rb + rr < 65) ? bm[rb + rr] : 0.0f;
                #pragma unroll
                for (int j = 0; j < 4; ++j) {
                    const int cb = j * 16 + l16;
                    ushort4v o;
                    #pragma unroll
                    for (int rr = 0; rr < 4; ++rr)
                        o[rr] = f2bf(sigm(acf[i][j][rr] + bv[rr]));
                    *(ushort4v*)&Gg[(size_t)cb * 4352 + rb] = o;
                }
            }
        }
    }
}

// ---- contraction: P[kc][n][b] partials; K=4352, K-split x4, 256 thr, 128x128 ----
__global__ __launch_bounds__(256, 3)
void contract_gemm(const unsigned short* __restrict__ XW,
                   const unsigned short* __restrict__ G,
                   float* __restrict__ P) {
    const int bid = blockIdx.x;
    const int xcd = bid & 7, slot = bid >> 3;          // 0..127
    const int kc  = slot >> 5;                          // 0..3
    const int rst = slot & 31;
    const int r0 = ((xcd << 2) + (rst >> 3)) << 7;      // n-tile (XCD-colocated)
    const int c0 = (rst & 7) << 7;                      // b-tile
    const int kb = kc * 1088;
    float* Pc = P + (size_t)kc * 4096 * 1024;

    __shared__ unsigned short As[128 * 64];
    __shared__ unsigned short Bs[128 * 64];

    const int tid = threadIdx.x;
    const int wave = tid >> 6, lane = tid & 63;
    const int quad = lane >> 4, l16 = lane & 15;
    const int wr = (wave & 1) * 64;
    const int wc = (wave >> 1) * 64;
    const int srow = wave * 32 + (lane >> 3);
    const int spos = lane & 7;

    floatx4 acc[4][4];
    const floatx4 zero = {0.f, 0.f, 0.f, 0.f};
    #pragma unroll
    for (int i = 0; i < 4; ++i)
        #pragma unroll
        for (int j = 0; j < 4; ++j) acc[i][j] = zero;

    for (int k0 = kb; k0 < kb + 1088; k0 += 64) {
        #pragma unroll
        for (int t = 0; t < 4; ++t) {
            const int row = srow + t * 8;
            const int fc  = spos ^ (row & 7);
            load_lds16(XW + (size_t)(r0 + row) * 4352 + k0 + fc * 8,
                       &As[(wave * 32 + t * 8) * 64]);
            load_lds16(G + (size_t)(c0 + row) * 4352 + k0 + fc * 8,
                       &Bs[(wave * 32 + t * 8) * 64]);
        }
        __syncthreads();

        #pragma unroll
        for (int kk = 0; kk < 2; ++kk) {
            short8 af[4], bfr[4];
            #pragma unroll
            for (int i = 0; i < 4; ++i) {
                const int ra = wr + i * 16 + l16;
                af[i]  = *(const short8*)&As[ra * 64 + (((kk * 4 + quad) ^ (ra & 7)) * 8)];
                const int cb = wc + i * 16 + l16;
                bfr[i] = *(const short8*)&Bs[cb * 64 + (((kk * 4 + quad) ^ (cb & 7)) * 8)];
            }
            #pragma unroll
            for (int i = 0; i < 4; ++i)
                #pragma unroll
                for (int j = 0; j < 4; ++j)
                    acc[i][j] = __builtin_amdgcn_mfma_f32_16x16x32_bf16(af[i], bfr[j], acc[i][j], 0, 0, 0);
        }
        __syncthreads();
    }

    #pragma unroll
    for (int i = 0; i < 4; ++i) {
        const int rb = r0 + wr + i * 16 + quad * 4;
        #pragma unroll
        for (int rr = 0; rr < 4; ++rr)
            #pragma unroll
            for (int j = 0; j < 4; ++j) {
                const int col = c0 + wc + j * 16 + l16;
                Pc[(size_t)(rb + rr) * 1024 + col] = acc[i][j][rr];
            }
    }
}

// ---- final reduce of 4 K-partials ----
__global__ void reduce4(const float* __restrict__ P, float* __restrict__ out) {
    const int i = blockIdx.x * 256 + threadIdx.x;
    const float4* p = (const float4*)P;
    float4 a = p[i], b = p[i + 1048576], c = p[i + 2097152], d = p[i + 3145728];
    ((float4*)out)[i] = (float4){ a.x + b.x + c.x + d.x, a.y + b.y + c.y + d.y,
                                  a.z + b.z + c.z + d.z, a.w + b.w + c.w + d.w };
}

extern "C" void kernel_launch(void* const* d_in, const int* in_sizes, int n_in,
                              void* d_out, int out_size, void* d_ws, size_t ws_size,
                              hipStream_t stream) {
    const float* u   = (const float*)d_in[0];
    const float* w0  = (const float*)d_in[1];
    const float* b0_ = (const float*)d_in[2];
    const float* w   = (const float*)d_in[3];
    const float* b   = (const float*)d_in[4];
    const float* wf  = (const float*)d_in[5];
    const float* bf_ = (const float*)d_in[6];
    const float* xi  = (const float*)d_in[7];
    float* out = (float*)d_out;

    unsigned short* w0_bf = (unsigned short*)d_ws;             // 1,048,576
    unsigned short* w_bf  = w0_bf + 1048576;                   // 12,582,912
    unsigned short* wf_bf = w_bf  + 12582912;                  // 2,097,152
    unsigned short* Gflat = wf_bf + 2097152;                   // 4,456,448 (1024 x 4352)
    unsigned short* XW    = Gflat + 4456448;                   // 17,825,792 (4096 x 4352)
    float*          P     = (float*)(XW + 17825792);           // 4 x 4096 x 1024 fp32

    prep<<<11776, 256, 0, stream>>>(w0, w, wf, xi, w0_bf, w_bf, wf_bf, (unsigned int*)XW);
    fused_mlp<<<1024, 256, 0, stream>>>(u, w0_bf, b0_, w_bf, b, wf_bf, bf_, Gflat);
    contract_gemm<<<1024, 256, 0, stream>>>(XW, Gflat, P);
    reduce4<<<4096, 256, 0, stream>>>(P, out);
}

// Round 10
// 229.975 us; speedup vs baseline: 1.8794x; 1.1418x over previous
//
#include <hip/hip_runtime.h>
#include <math.h>

typedef __attribute__((ext_vector_type(8))) short short8;
typedef __attribute__((ext_vector_type(4))) float floatx4;
typedef __attribute__((ext_vector_type(4))) unsigned short ushort4v;

__device__ __forceinline__ void load_lds16(const void* g, void* l) {
    __builtin_amdgcn_global_load_lds((const __attribute__((address_space(1))) void*)g,
                                     (__attribute__((address_space(3))) void*)l,
                                     16, 0, 0);
}

__device__ __forceinline__ unsigned short f2bf(float x) {
    union { float f; unsigned int u; } v; v.f = x;
    unsigned int r = v.u + 0x7fffu + ((v.u >> 16) & 1u);
    return (unsigned short)(r >> 16);
}

// pack two fp32 -> two bf16 (round-half-up) in one v_perm_b32
__device__ __forceinline__ unsigned int pack_bf(float f0, float f1) {
    union { float f; unsigned int u; } a, b;
    a.f = f0; b.f = f1;
    return __builtin_amdgcn_perm(b.u + 0x8000u, a.u + 0x8000u, 0x07060302u);
}

__device__ __forceinline__ float fast_exp2(float x) {
#if __has_builtin(__builtin_amdgcn_exp2f)
    return __builtin_amdgcn_exp2f(x);
#else
    return __expf(x * 0.69314718056f);
#endif
}

__device__ __forceinline__ float fast_rcp(float x) {
#if __has_builtin(__builtin_amdgcn_rcpf)
    return __builtin_amdgcn_rcpf(x);
#else
    return 1.0f / x;
#endif
}

#define NEG_LOG2E (-1.4426950408889634f)

__device__ __forceinline__ float sigm(float x) { return 1.0f / (1.0f + __expf(-x)); }

// ---- prep: weights -> bf16 in MFMA-fragment order + Toeplitz XW build ----
// blocks: [0,512) w0 | [512,6656) w | [6656,7680) wf-pad | [7680,11776) XW rows
__global__ void prep(const float* __restrict__ w0, const float* __restrict__ w,
                     const float* __restrict__ wf, const float* __restrict__ xi,
                     unsigned short* __restrict__ w0d, unsigned short* __restrict__ wd,
                     unsigned short* __restrict__ wfd, unsigned int* __restrict__ xw) {
    const int bid = blockIdx.x;
    if (bid < 6656) {
        const bool is0 = bid < 512;
        const int c = (is0 ? bid : bid - 512) * 256 + threadIdx.x;
        const int cpm = is0 ? 2048 : 8192;
        const int Kk  = is0 ? 2 : 8;
        const int K   = Kk * 32;
        const int mm  = c / cpm;
        const int cm  = c - mm * cpm;
        const int rblk = cm / (Kk * 64);
        const int rem  = cm - rblk * (Kk * 64);
        const int kk   = rem >> 6;
        const int lane = rem & 63;
        const int r  = rblk * 16 + (lane & 15);
        const int k0 = kk * 32 + (lane >> 4) * 8;
        const float* srcp = (is0 ? w0 : w) + ((size_t)mm * 256 + r) * K + k0;
        unsigned short* dstp = (is0 ? w0d : wd) + (size_t)c * 8;
        float4 a = *(const float4*)srcp;
        float4 b = *(const float4*)(srcp + 4);
        short8 o = { (short)f2bf(a.x), (short)f2bf(a.y), (short)f2bf(a.z), (short)f2bf(a.w),
                     (short)f2bf(b.x), (short)f2bf(b.y), (short)f2bf(b.z), (short)f2bf(b.w) };
        *(short8*)dstp = o;
    } else if (bid < 7680) {
        const int c = (bid - 6656) * 256 + threadIdx.x;
        const int m  = c >> 12;
        const int cm = c & 4095;
        const int rblk = cm >> 9;
        const int rem  = cm & 511;
        const int kk   = rem >> 6;
        const int lane = rem & 63;
        const int r  = rblk * 16 + (lane & 15);
        const int k0 = kk * 32 + (lane >> 4) * 8;
        short8 o = {0,0,0,0,0,0,0,0};
        if (r < 65) {
            const float* srcp = wf + ((size_t)m * 65 + r) * 256 + k0;
            float4 a = *(const float4*)srcp;
            float4 b = *(const float4*)(srcp + 4);
            o = (short8){ (short)f2bf(a.x), (short)f2bf(a.y), (short)f2bf(a.z), (short)f2bf(a.w),
                          (short)f2bf(b.x), (short)f2bf(b.y), (short)f2bf(b.z), (short)f2bf(b.w) };
        }
        *(short8*)(wfd + (size_t)c * 8) = o;
    } else {
        const int n = bid - 7680;
        #pragma unroll
        for (int t = 0; t < 9; ++t) {
            const int idx = t * 256 + threadIdx.x;
            if (idx < 2176) {
                const int m = idx / 34;
                const int pos = idx - m * 34;
                const int j0 = pos * 2;
                const float* xim = xi + (size_t)m * 4160 + n;
                const float v0 = (j0 < 65) ? xim[j0] : 0.0f;
                const float v1 = (j0 + 1 < 65) ? xim[j0 + 1] : 0.0f;
                xw[(size_t)n * 2176 + idx] =
                    (unsigned int)f2bf(v0) | ((unsigned int)f2bf(v1) << 16);
            }
        }
    }
}

// ---- one MLP layer: weights from global in fragment order (coalesced), X in LDS ----
// X layout: X[b][k] at b*K + ((k/8) ^ (b&7))*8 + (k&7)   (shorts)
template<int K, int I>
__device__ __forceinline__ void mlp_mfma(
    const unsigned short* __restrict__ Wt, const unsigned short* src,
    int wave, int lane, floatx4 (*acc)[4])
{
    const int Kk = K / 32;
    const int quad = lane >> 4, l16 = lane & 15;
    const int rblk0 = wave * I;
    const floatx4 zero = {0.f, 0.f, 0.f, 0.f};
    #pragma unroll
    for (int i = 0; i < I; ++i)
        #pragma unroll
        for (int j = 0; j < 4; ++j) acc[i][j] = zero;

    #pragma unroll
    for (int kk = 0; kk < Kk; ++kk) {
        short8 af[I], bf[4];
        #pragma unroll
        for (int i = 0; i < I; ++i)
            af[i] = *(const short8*)&Wt[(size_t)(((rblk0 + i) * Kk + kk) * 64 + lane) * 8];
        #pragma unroll
        for (int j = 0; j < 4; ++j) {
            const int cb = j * 16 + l16;
            bf[j] = *(const short8*)&src[cb * K + (((kk * 4 + quad) ^ (cb & 7)) * 8)];
        }
        #pragma unroll
        for (int i = 0; i < I; ++i)
            #pragma unroll
            for (int j = 0; j < 4; ++j)
                acc[i][j] = __builtin_amdgcn_mfma_f32_16x16x32_bf16(af[i], bf[j], acc[i][j], 0, 0, 0);
    }
}

// epilogue: fused bias+sigmoid via fma/exp2/rcp, round-half-up perm pack,
// in-place into the same X buffer (K_out=256 layout)
__device__ __forceinline__ void mlp_write(
    const float* __restrict__ bm, unsigned short* dst,
    int wave, int lane, floatx4 (*acc)[4])
{
    const int quad = lane >> 4, l16 = lane & 15;
    const int rbw = wave * 64;
    #pragma unroll
    for (int i = 0; i < 4; ++i) {
        const int rb = rbw + i * 16 + quad * 4;
        float c0 = bm[rb]     * NEG_LOG2E;
        float c1 = bm[rb + 1] * NEG_LOG2E;
        float c2 = bm[rb + 2] * NEG_LOG2E;
        float c3 = bm[rb + 3] * NEG_LOG2E;
        #pragma unroll
        for (int j = 0; j < 4; ++j) {
            const int cb = j * 16 + l16;
            float r0 = fast_rcp(1.0f + fast_exp2(fmaf(acc[i][j][0], NEG_LOG2E, c0)));
            float r1 = fast_rcp(1.0f + fast_exp2(fmaf(acc[i][j][1], NEG_LOG2E, c1)));
            float r2 = fast_rcp(1.0f + fast_exp2(fmaf(acc[i][j][2], NEG_LOG2E, c2)));
            float r3 = fast_rcp(1.0f + fast_exp2(fmaf(acc[i][j][3], NEG_LOG2E, c3)));
            uint2 o = { pack_bf(r0, r1), pack_bf(r2, r3) };
            *(uint2*)&dst[cb * 256 + (((rb >> 3) ^ (cb & 7)) * 8) + (rb & 7)] = o;
        }
    }
}

// ---- fused MLP: 5 layers, single 32 KB in-place activation buffer ----
// grid 1024 = 64 m x 16 batch-tiles (XCD-swizzled), 256 threads.
// (256,3): 3 blocks/CU; no weight prefetch (coalesced single-address loads).
__global__ __launch_bounds__(256, 3)
void fused_mlp(const float* __restrict__ u,
               const unsigned short* __restrict__ w0_bf, const float* __restrict__ b0_,
               const unsigned short* __restrict__ w_bf,  const float* __restrict__ b_,
               const unsigned short* __restrict__ wf_bf, const float* __restrict__ bf_,
               unsigned short* __restrict__ Gflat) {
    __shared__ unsigned short X[64 * 256];   // 32 KB

    const int bid = blockIdx.x;
    const int xcd = bid & 7, slot = bid >> 3;
    const int m  = (xcd << 3) + (slot >> 4);
    const int b0 = (slot & 15) << 6;
    const int tid = threadIdx.x, wave = tid >> 6, lane = tid & 63;

    // stage u (fp32) -> X (bf16, K=64 layout), perm-packed
    {
        const int b = tid >> 2, dc = tid & 3;
        const float* up = u + (size_t)(b0 + b) * 64 + dc * 16;
        float4 v0 = *(const float4*)(up);
        float4 v1 = *(const float4*)(up + 4);
        float4 v2 = *(const float4*)(up + 8);
        float4 v3 = *(const float4*)(up + 12);
        uint4 p0 = { pack_bf(v0.x, v0.y), pack_bf(v0.z, v0.w),
                     pack_bf(v1.x, v1.y), pack_bf(v1.z, v1.w) };
        uint4 p1 = { pack_bf(v2.x, v2.y), pack_bf(v2.z, v2.w),
                     pack_bf(v3.x, v3.y), pack_bf(v3.z, v3.w) };
        *(uint4*)&X[b * 64 + (((dc * 2)     ^ (b & 7)) * 8)] = p0;
        *(uint4*)&X[b * 64 + (((dc * 2 + 1) ^ (b & 7)) * 8)] = p1;
    }
    __syncthreads();

    floatx4 acc[4][4];

    mlp_mfma<64, 4>(w0_bf + (size_t)m * 16384, X, wave, lane, acc);
    __syncthreads();
    mlp_write(b0_ + (size_t)m * 256, X, wave, lane, acc);
    __syncthreads();

    #pragma unroll 1
    for (int l = 0; l < 3; ++l) {
        mlp_mfma<256, 4>(w_bf + ((size_t)l * 64 + m) * 65536, X, wave, lane, acc);
        __syncthreads();
        mlp_write(b_ + ((size_t)l * 64 + m) * 256, X, wave, lane, acc);
        __syncthreads();
    }

    {
        floatx4 acf[2][4];
        mlp_mfma<256, 2>(wf_bf + (size_t)m * 32768, X, wave, lane, acf);
        const int quad = lane >> 4, l16 = lane & 15;
        const float* bm = bf_ + (size_t)m * 65;
        unsigned short* Gg = Gflat + (size_t)b0 * 4352 + m * 68;
        #pragma unroll
        for (int i = 0; i < 2; ++i) {
            const int rb = wave * 32 + i * 16 + quad * 4;
            if (rb < 68) {
                float c[4];
                #pragma unroll
                for (int rr = 0; rr < 4; ++rr)
                    c[rr] = (rb + rr < 65) ? bm[rb + rr] * NEG_LOG2E : 0.0f;
                #pragma unroll
                for (int j = 0; j < 4; ++j) {
                    const int cb = j * 16 + l16;
                    float r0 = fast_rcp(1.0f + fast_exp2(fmaf(acf[i][j][0], NEG_LOG2E, c[0])));
                    float r1 = fast_rcp(1.0f + fast_exp2(fmaf(acf[i][j][1], NEG_LOG2E, c[1])));
                    float r2 = fast_rcp(1.0f + fast_exp2(fmaf(acf[i][j][2], NEG_LOG2E, c[2])));
                    float r3 = fast_rcp(1.0f + fast_exp2(fmaf(acf[i][j][3], NEG_LOG2E, c[3])));
                    uint2 o = { pack_bf(r0, r1), pack_bf(r2, r3) };
                    *(uint2*)&Gg[(size_t)cb * 4352 + rb] = o;
                }
            }
        }
    }
}

// ---- contraction: P[kc][n][b] partials; K=4352, K-split x4, 256 thr, 128x128 ----
__global__ __launch_bounds__(256, 3)
void contract_gemm(const unsigned short* __restrict__ XW,
                   const unsigned short* __restrict__ G,
                   float* __restrict__ P) {
    const int bid = blockIdx.x;
    const int xcd = bid & 7, slot = bid >> 3;          // 0..127
    const int kc  = slot >> 5;                          // 0..3
    const int rst = slot & 31;
    const int r0 = ((xcd << 2) + (rst >> 3)) << 7;      // n-tile (XCD-colocated)
    const int c0 = (rst & 7) << 7;                      // b-tile
    const int kb = kc * 1088;
    float* Pc = P + (size_t)kc * 4096 * 1024;

    __shared__ unsigned short As[128 * 64];
    __shared__ unsigned short Bs[128 * 64];

    const int tid = threadIdx.x;
    const int wave = tid >> 6, lane = tid & 63;
    const int quad = lane >> 4, l16 = lane & 15;
    const int wr = (wave & 1) * 64;
    const int wc = (wave >> 1) * 64;
    const int srow = wave * 32 + (lane >> 3);
    const int spos = lane & 7;

    floatx4 acc[4][4];
    const floatx4 zero = {0.f, 0.f, 0.f, 0.f};
    #pragma unroll
    for (int i = 0; i < 4; ++i)
        #pragma unroll
        for (int j = 0; j < 4; ++j) acc[i][j] = zero;

    for (int k0 = kb; k0 < kb + 1088; k0 += 64) {
        #pragma unroll
        for (int t = 0; t < 4; ++t) {
            const int row = srow + t * 8;
            const int fc  = spos ^ (row & 7);
            load_lds16(XW + (size_t)(r0 + row) * 4352 + k0 + fc * 8,
                       &As[(wave * 32 + t * 8) * 64]);
            load_lds16(G + (size_t)(c0 + row) * 4352 + k0 + fc * 8,
                       &Bs[(wave * 32 + t * 8) * 64]);
        }
        __syncthreads();

        #pragma unroll
        for (int kk = 0; kk < 2; ++kk) {
            short8 af[4], bfr[4];
            #pragma unroll
            for (int i = 0; i < 4; ++i) {
                const int ra = wr + i * 16 + l16;
                af[i]  = *(const short8*)&As[ra * 64 + (((kk * 4 + quad) ^ (ra & 7)) * 8)];
                const int cb = wc + i * 16 + l16;
                bfr[i] = *(const short8*)&Bs[cb * 64 + (((kk * 4 + quad) ^ (cb & 7)) * 8)];
            }
            #pragma unroll
            for (int i = 0; i < 4; ++i)
                #pragma unroll
                for (int j = 0; j < 4; ++j)
                    acc[i][j] = __builtin_amdgcn_mfma_f32_16x16x32_bf16(af[i], bfr[j], acc[i][j], 0, 0, 0);
        }
        __syncthreads();
    }

    #pragma unroll
    for (int i = 0; i < 4; ++i) {
        const int rb = r0 + wr + i * 16 + quad * 4;
        #pragma unroll
        for (int rr = 0; rr < 4; ++rr)
            #pragma unroll
            for (int j = 0; j < 4; ++j) {
                const int col = c0 + wc + j * 16 + l16;
                Pc[(size_t)(rb + rr) * 1024 + col] = acc[i][j][rr];
            }
    }
}

// ---- final reduce of 4 K-partials ----
__global__ void reduce4(const float* __restrict__ P, float* __restrict__ out) {
    const int i = blockIdx.x * 256 + threadIdx.x;
    const float4* p = (const float4*)P;
    float4 a = p[i], b = p[i + 1048576], c = p[i + 2097152], d = p[i + 3145728];
    ((float4*)out)[i] = (float4){ a.x + b.x + c.x + d.x, a.y + b.y + c.y + d.y,
                                  a.z + b.z + c.z + d.z, a.w + b.w + c.w + d.w };
}

extern "C" void kernel_launch(void* const* d_in, const int* in_sizes, int n_in,
                              void* d_out, int out_size, void* d_ws, size_t ws_size,
                              hipStream_t stream) {
    const float* u   = (const float*)d_in[0];
    const float* w0  = (const float*)d_in[1];
    const float* b0_ = (const float*)d_in[2];
    const float* w   = (const float*)d_in[3];
    const float* b   = (const float*)d_in[4];
    const float* wf  = (const float*)d_in[5];
    const float* bf_ = (const float*)d_in[6];
    const float* xi  = (const float*)d_in[7];
    float* out = (float*)d_out;

    unsigned short* w0_bf = (unsigned short*)d_ws;             // 1,048,576
    unsigned short* w_bf  = w0_bf + 1048576;                   // 12,582,912
    unsigned short* wf_bf = w_bf  + 12582912;                  // 2,097,152
    unsigned short* Gflat = wf_bf + 2097152;                   // 4,456,448 (1024 x 4352)
    unsigned short* XW    = Gflat + 4456448;                   // 17,825,792 (4096 x 4352)
    float*          P     = (float*)(XW + 17825792);           // 4 x 4096 x 1024 fp32

    prep<<<11776, 256, 0, stream>>>(w0, w, wf, xi, w0_bf, w_bf, wf_bf, (unsigned int*)XW);
    fused_mlp<<<1024, 256, 0, stream>>>(u, w0_bf, b0_, w_bf, b, wf_bf, bf_, Gflat);
    contract_gemm<<<1024, 256, 0, stream>>>(XW, Gflat, P);
    reduce4<<<4096, 256, 0, stream>>>(P, out);
}